// Round 12
// baseline (1920.076 us; speedup 1.0000x reference)
//
#include <hip/hip_runtime.h>
#include <cstdint>
#include <cstddef>

// Problem constants
#define BB 4
#define SS 4096
#define HH 1024
#define PP 10
#define LL 4106              // P + S
#define NTILES 129
#define CHUNKS_PB (NTILES * 4096)   // 16B-chunks per batch plane (= 528384)
#define TILE_ELEMS (4096 * 8)       // fp16 elems per tile in a plane
#define LOG2E 1.44269504088896f

typedef __attribute__((ext_vector_type(8))) _Float16 half8v;  // 4 VGPR MFMA frag
typedef __attribute__((ext_vector_type(4))) float float4v;

union hu16 { _Float16 h; unsigned short u; };

__device__ __forceinline__ half8v cvt8h(float4v f0, float4v f1) {
  half8v h;
  h[0] = (_Float16)f0[0]; h[1] = (_Float16)f0[1];
  h[2] = (_Float16)f0[2]; h[3] = (_Float16)f0[3];
  h[4] = (_Float16)f1[0]; h[5] = (_Float16)f1[1];
  h[6] = (_Float16)f1[2]; h[7] = (_Float16)f1[3];
  return h;
}
__device__ __forceinline__ unsigned pack2h(float a, float b) {
  hu16 x, y; x.h = (_Float16)a; y.h = (_Float16)b;
  return (unsigned)x.u | ((unsigned)y.u << 16);
}

// DPP lane permute within 16-lane rows (VALU pipe).
template<int C>
__device__ __forceinline__ float dppf(float x) {
  return __int_as_float(
      __builtin_amdgcn_update_dpp(0, __float_as_int(x), C, 0xF, 0xF, true));
}
__device__ __forceinline__ float row16_max(float x) {
  x = fmaxf(x, dppf<0xB1>(x));
  x = fmaxf(x, dppf<0x4E>(x));
  x = fmaxf(x, dppf<0x140>(x));
  x = fmaxf(x, dppf<0x141>(x));
  return x;
}
__device__ __forceinline__ float row16_sum(float x) {
  x += dppf<0xB1>(x);
  x += dppf<0x4E>(x);
  x += dppf<0x140>(x);
  x += dppf<0x141>(x);
  return x;
}

// raw barrier: drain own LDS ops, no vmcnt drain (keeps global loads in flight)
#define LGKM_BAR() do { \
  asm volatile("s_waitcnt lgkmcnt(0)" ::: "memory"); \
  __builtin_amdgcn_s_barrier(); \
  asm volatile("" ::: "memory"); } while (0)

// ---------- pre-kernels: fp16 planes in MFMA-fragment order (unchanged) ----------
__global__ __launch_bounds__(256) void conv_k(const float* __restrict__ prefix_k,
                                              const float* __restrict__ key,
                                              _Float16* __restrict__ kp) {
  const int b = blockIdx.y;
  const int id = blockIdx.x * 256 + threadIdx.x;       // < CHUNKS_PB
  const int li = id & 15, g = (id >> 4) & 3, ktp = (id >> 6) & 31,
            nt = (id >> 11) & 1, it = id >> 12;
  const int n = it * 32 + nt * 16 + li;
  const int d = ktp * 32 + g * 8;
  float4v f0 = {0.f, 0.f, 0.f, 0.f}, f1 = {0.f, 0.f, 0.f, 0.f};
  if (n < LL) {
    const float* src = (n < PP) ? prefix_k + (size_t)n * HH + d
                                : key + ((size_t)b * SS + (n - PP)) * HH + d;
    f0 = *(const float4v*)src; f1 = *(const float4v*)(src + 4);
  }
  *(half8v*)(kp + ((size_t)b * CHUNKS_PB + id) * 8) = cvt8h(f0, f1);
}

__global__ __launch_bounds__(256) void conv_v(const float* __restrict__ prefix_v,
                                              const float* __restrict__ value,
                                              _Float16* __restrict__ vp) {
  const int b = blockIdx.y;
  const int id = blockIdx.x * 256 + threadIdx.x;
  const int d = id & 1023, g = (id >> 10) & 3, it = id >> 12;
  const int nb = it * 32 + g * 8;
  half8v h;
  #pragma unroll
  for (int j = 0; j < 8; ++j) {
    int n = nb + j;
    float f = 0.f;
    if (n < LL)
      f = (n < PP) ? prefix_v[(size_t)n * HH + d]
                   : value[((size_t)b * SS + (n - PP)) * HH + d];
    h[j] = (_Float16)f;
  }
  *(half8v*)(vp + ((size_t)b * CHUNKS_PB + id) * 8) = h;
}

// ---------------- fused flash attention, v12: v7 + 2 blocks/CU ----------------
// Identical per-wave structure to v7 (426 us): 8 waves, D-128/wave, M=32,
// 1 barrier/iter, 3-deep pipeline, DPP softmax, named LDS banks.
// Changes: sbuf stride 36->34 (LDS 79.4->75.1 KB so TWO blocks fit per CU) and
// __launch_bounds__(512,4) (4 waves/EU -> 2 blocks/CU; VGPR cap 128 >= v7's 120).
// Two co-resident blocks overlap: one block's barrier/L2 stalls are hidden
// under the other's MFMA/VALU.
template<int PATH>
__global__ __launch_bounds__(512, 4) void attn_fused(
    const float* __restrict__ q,
    const float* __restrict__ key,
    const float* __restrict__ value,
    const float* __restrict__ prefix_k,
    const float* __restrict__ prefix_v,
    const _Float16* __restrict__ kp,
    const _Float16* __restrict__ vp,
    float* __restrict__ out)
{
  __shared__ __align__(16) float sbuf0[8][32][34];        // 34.8 KB, bank 0 (even tiles)
  __shared__ __align__(16) float sbuf1[8][32][34];        // bank 1 (odd tiles)
  __shared__ __align__(16) unsigned short Pl0[32][40];
  __shared__ __align__(16) unsigned short Pl1[32][40];
  __shared__ float sc0[32], sc1[32];
  __shared__ float l_l[32];

  const int tid = threadIdx.x;
  const int w = tid >> 6, ln = tid & 63, g = ln >> 4, li = ln & 15;
  const int bid = blockIdx.x, xcd = bid & 7, b = xcd >> 1;
  const int qt = ((bid >> 3) << 1) | (xcd & 1);
  const int q0 = qt * 32;
  const int dbase = w * 128;

  // Q fragments fp16: A-layout row=li, k=g*8+j
  half8v qf[2][4];
  #pragma unroll
  for (int mt = 0; mt < 2; ++mt)
    #pragma unroll
    for (int kt = 0; kt < 4; ++kt) {
      const float* p = q + ((size_t)(b * SS + q0 + mt * 16 + li)) * HH + dbase + kt * 32 + g * 8;
      qf[mt][kt] = cvt8h(*(const float4v*)p, *(const float4v*)(p + 4));
    }

  float4v z4 = {0.f, 0.f, 0.f, 0.f};
  float4v o[2][8];
  #pragma unroll
  for (int mt = 0; mt < 2; ++mt)
    #pragma unroll
    for (int dt = 0; dt < 8; ++dt) o[mt][dt] = z4;
  float m_r = -1e30f, l_r = 0.f;

  const _Float16* kbase = kp + ((size_t)b * CHUNKS_PB + (size_t)(w * 4) * 64 + g * 16 + li) * 8;
  const _Float16* vbase = vp + ((size_t)b * CHUNKS_PB + (size_t)g * 1024 + dbase + li) * 8;

  half8v kreg[8];   // K(i) during iter i
  half8v vreg[8];   // V(i-2) during iter i
  if constexpr (PATH == 0) {
    #pragma unroll
    for (int kt = 0; kt < 4; ++kt)
      #pragma unroll
      for (int nt = 0; nt < 2; ++nt)
        kreg[kt * 2 + nt] = *(const half8v*)(kbase + (size_t)(nt * 2048 + kt * 64) * 8);
  }

  const int srow = w * 4 + (ln >> 4);     // slab row this lane helps with
  const int c0 = (ln & 15) * 2;

  // ---- phase helpers; bank arrays passed as compile-time-known pointers ----
  auto do_qk = [&](int i, float (*sb)[32][34]) __attribute__((always_inline)) {
    float4v sacc[2][2];
    sacc[0][0] = z4; sacc[0][1] = z4; sacc[1][0] = z4; sacc[1][1] = z4;
    #pragma unroll
    for (int kt = 0; kt < 4; ++kt) {
      half8v kb[2];
      if constexpr (PATH == 0) {
        kb[0] = kreg[kt * 2 + 0]; kb[1] = kreg[kt * 2 + 1];
      } else {
        #pragma unroll
        for (int nt = 0; nt < 2; ++nt) {
          int n = i * 32 + nt * 16 + li;
          int nc = (n < LL) ? n : 0;
          const float* kpp = (nc < PP) ? (prefix_k + (size_t)nc * HH)
                                       : (key + ((size_t)b * SS + (nc - PP)) * HH);
          kpp += dbase + kt * 32 + g * 8;
          kb[nt] = cvt8h(*(const float4v*)kpp, *(const float4v*)(kpp + 4));
        }
      }
      #pragma unroll
      for (int mt = 0; mt < 2; ++mt)
        #pragma unroll
        for (int nt = 0; nt < 2; ++nt)
          sacc[mt][nt] = __builtin_amdgcn_mfma_f32_16x16x32_f16(qf[mt][kt], kb[nt], sacc[mt][nt], 0, 0, 0);
    }
    // C/D: row = g*4+r, col = li
    #pragma unroll
    for (int mt = 0; mt < 2; ++mt)
      #pragma unroll
      for (int nt = 0; nt < 2; ++nt)
        #pragma unroll
        for (int r = 0; r < 4; ++r)
          sb[w][mt * 16 + g * 4 + r][nt * 16 + li] = sacc[mt][nt][r];
    // prefetch kreg <- K(i+1)  (benign 1-tile overrun into vp after last tile)
    if constexpr (PATH == 0) {
      kbase += TILE_ELEMS;
      #pragma unroll
      for (int kt = 0; kt < 4; ++kt)
        #pragma unroll
        for (int nt = 0; nt < 2; ++nt)
          kreg[kt * 2 + nt] = *(const half8v*)(kbase + (size_t)(nt * 2048 + kt * 64) * 8);
    }
  };

  auto do_softmax = [&](int t, const float (*sb)[32][34],
                        unsigned short (*plw)[40], float* scw)
      __attribute__((always_inline)) {
    float s0 = 0.f, s1 = 0.f;
    #pragma unroll
    for (int bw = 0; bw < 8; ++bw) {
      float2 tv = *(const float2*)&sb[bw][srow][c0];
      s0 += tv.x; s1 += tv.y;
    }
    if constexpr (PATH == 1) {
      if (t * 32 + c0 >= LL)     s0 = -1e30f;
      if (t * 32 + c0 + 1 >= LL) s1 = -1e30f;
    }
    const float mx = row16_max(fmaxf(s0, s1));      // DPP, VALU pipe
    const float m_new = fmaxf(m_r, mx);
    const float scp = exp2f((m_r - m_new) * LOG2E);
    const float p0 = exp2f((s0 - m_new) * LOG2E);
    const float p1 = exp2f((s1 - m_new) * LOG2E);
    const float ts = row16_sum(p0 + p1);            // DPP, VALU pipe
    l_r = l_r * scp + ts;
    m_r = m_new;
    *(unsigned*)&plw[srow][c0] = pack2h(p0, p1);
    if ((ln & 15) == 0) scw[srow] = scp;
  };

  auto do_pv = [&](int t, const unsigned short (*plr)[40], const float* scr)
      __attribute__((always_inline)) {
    float scc[2][4];
    #pragma unroll
    for (int mt = 0; mt < 2; ++mt)
      #pragma unroll
      for (int r = 0; r < 4; ++r)
        scc[mt][r] = scr[mt * 16 + g * 4 + r];
    #pragma unroll
    for (int mt = 0; mt < 2; ++mt)
      #pragma unroll
      for (int dt = 0; dt < 8; ++dt)
        #pragma unroll
        for (int r = 0; r < 4; ++r)
          o[mt][dt][r] *= scc[mt][r];
    half8v pa0 = *(const half8v*)&plr[li][g * 8];
    half8v pa1 = *(const half8v*)&plr[16 + li][g * 8];
    #pragma unroll
    for (int dt = 0; dt < 8; ++dt) {
      half8v vb;
      if constexpr (PATH == 0) {
        vb = vreg[dt];
      } else {
        const int d = dbase + dt * 16 + li;
        #pragma unroll
        for (int j = 0; j < 8; ++j) {
          int n = t * 32 + g * 8 + j;
          int nc = (n < LL) ? n : 0;    // clamped rows have P==0
          float f = (nc < PP) ? prefix_v[(size_t)nc * HH + d]
                              : value[((size_t)b * SS + (nc - PP)) * HH + d];
          vb[j] = (_Float16)f;
        }
      }
      o[0][dt] = __builtin_amdgcn_mfma_f32_16x16x32_f16(pa0, vb, o[0][dt], 0, 0, 0);
      o[1][dt] = __builtin_amdgcn_mfma_f32_16x16x32_f16(pa1, vb, o[1][dt], 0, 0, 0);
    }
  };

  auto load_v = [&]() __attribute__((always_inline)) {
    if constexpr (PATH == 0) {
      #pragma unroll
      for (int dt = 0; dt < 8; ++dt)
        vreg[dt] = *(const half8v*)(vbase + (size_t)(dt * 16) * 8);
      vbase += TILE_ELEMS;
    }
  };

  // ---- pipeline: prologue / steady (x2 unrolled) / epilogue ----
  // parity: qk(i)->sbuf(i&1); sm(t): reads sbuf(t&1), writes Pl(t&1)/sc(t&1);
  //         pv(t): reads Pl(t&1)/sc(t&1), consumes vreg=V(t).
  // region order: QK -> PV -> softmax (PV independent of this iter's softmax).
  do_qk(0, sbuf0);
  LGKM_BAR();
  do_qk(1, sbuf1); do_softmax(0, sbuf0, Pl0, sc0); load_v();
  LGKM_BAR();
  int i = 2;
  for (; i + 1 < NTILES; i += 2) {
    do_qk(i, sbuf0);
    do_pv(i - 2, Pl0, sc0);
    do_softmax(i - 1, sbuf1, Pl1, sc1);
    load_v();
    LGKM_BAR();
    do_qk(i + 1, sbuf1);
    do_pv(i - 1, Pl1, sc1);
    do_softmax(i, sbuf0, Pl0, sc0);
    load_v();
    LGKM_BAR();
  }
  // NTILES odd: one remaining even-bank steady iter (i == NTILES-1 == 128)
  do_qk(NTILES - 1, sbuf0);
  do_pv(NTILES - 3, Pl0, sc0);
  do_softmax(NTILES - 2, sbuf1, Pl1, sc1);
  load_v();
  LGKM_BAR();
  // epilogue
  do_pv(NTILES - 2, Pl1, sc1);
  do_softmax(NTILES - 1, sbuf0, Pl0, sc0);
  load_v();
  LGKM_BAR();
  do_pv(NTILES - 1, Pl0, sc0);

  // ---- finalize ----
  if ((ln & 15) == 0) l_l[srow] = l_r;
  LGKM_BAR();
  float il[2][4];
  #pragma unroll
  for (int mt = 0; mt < 2; ++mt)
    #pragma unroll
    for (int r = 0; r < 4; ++r)
      il[mt][r] = 1.0f / l_l[mt * 16 + g * 4 + r];
  #pragma unroll
  for (int mt = 0; mt < 2; ++mt)
    #pragma unroll
    for (int dt = 0; dt < 8; ++dt)
      #pragma unroll
      for (int r = 0; r < 4; ++r)
        out[((size_t)(b * SS + q0 + mt * 16 + g * 4 + r)) * HH + dbase + dt * 16 + li]
            = o[mt][dt][r] * il[mt][r];
}

extern "C" void kernel_launch(void* const* d_in, const int* in_sizes, int n_in,
                              void* d_out, int out_size, void* d_ws, size_t ws_size,
                              hipStream_t stream) {
  const float* q        = (const float*)d_in[0];
  const float* key      = (const float*)d_in[1];
  const float* value    = (const float*)d_in[2];
  const float* prefix_k = (const float*)d_in[3];
  const float* prefix_v = (const float*)d_in[4];
  float* out = (float*)d_out;

  const size_t PLANE = (size_t)BB * CHUNKS_PB * 8;              // fp16 elems per plane
  const size_t NEED  = 2 * PLANE * sizeof(unsigned short);      // 67.6 MB

  if (ws_size >= NEED) {
    _Float16* kp = (_Float16*)d_ws;
    _Float16* vp = kp + PLANE;
    conv_k<<<dim3(CHUNKS_PB / 256, BB), 256, 0, stream>>>(prefix_k, key, kp);
    conv_v<<<dim3(CHUNKS_PB / 256, BB), 256, 0, stream>>>(prefix_v, value, vp);
    attn_fused<0><<<512, 512, 0, stream>>>(q, key, value, prefix_k, prefix_v, kp, vp, out);
  } else {
    attn_fused<1><<<512, 512, 0, stream>>>(q, key, value, prefix_k, prefix_v,
                                           nullptr, nullptr, out);
  }
}

// Round 13
// 405.429 us; speedup vs baseline: 4.7359x; 4.7359x over previous
//
#include <hip/hip_runtime.h>
#include <cstdint>
#include <cstddef>

// Problem constants
#define BB 4
#define SS 4096
#define HH 1024
#define PP 10
#define LL 4106              // P + S
#define NTILES 129
#define CHUNKS_PB (NTILES * 4096)   // 16B-chunks per batch plane (= 528384)
#define TILE_ELEMS (4096 * 8)       // fp16 elems per tile in a plane
#define LOG2E 1.44269504088896f

typedef __attribute__((ext_vector_type(8))) _Float16 half8v;  // 4 VGPR MFMA frag
typedef __attribute__((ext_vector_type(4))) float float4v;

union hu16 { _Float16 h; unsigned short u; };

__device__ __forceinline__ half8v cvt8h(float4v f0, float4v f1) {
  half8v h;
  h[0] = (_Float16)f0[0]; h[1] = (_Float16)f0[1];
  h[2] = (_Float16)f0[2]; h[3] = (_Float16)f0[3];
  h[4] = (_Float16)f1[0]; h[5] = (_Float16)f1[1];
  h[6] = (_Float16)f1[2]; h[7] = (_Float16)f1[3];
  return h;
}
__device__ __forceinline__ unsigned pack2h(float a, float b) {
  hu16 x, y; x.h = (_Float16)a; y.h = (_Float16)b;
  return (unsigned)x.u | ((unsigned)y.u << 16);
}

// DPP lane permute within 16-lane rows (VALU pipe).
template<int C>
__device__ __forceinline__ float dppf(float x) {
  return __int_as_float(
      __builtin_amdgcn_update_dpp(0, __float_as_int(x), C, 0xF, 0xF, true));
}
__device__ __forceinline__ float row16_max(float x) {
  x = fmaxf(x, dppf<0xB1>(x));
  x = fmaxf(x, dppf<0x4E>(x));
  x = fmaxf(x, dppf<0x140>(x));
  x = fmaxf(x, dppf<0x141>(x));
  return x;
}
__device__ __forceinline__ float row16_sum(float x) {
  x += dppf<0xB1>(x);
  x += dppf<0x4E>(x);
  x += dppf<0x140>(x);
  x += dppf<0x141>(x);
  return x;
}

// raw barrier: drain own LDS ops, no vmcnt drain (keeps global loads in flight)
#define LGKM_BAR() do { \
  asm volatile("s_waitcnt lgkmcnt(0)" ::: "memory"); \
  __builtin_amdgcn_s_barrier(); \
  asm volatile("" ::: "memory"); } while (0)

// ---------- pre-kernels: fp16 planes in MFMA-fragment order (unchanged) ----------
__global__ __launch_bounds__(256) void conv_k(const float* __restrict__ prefix_k,
                                              const float* __restrict__ key,
                                              _Float16* __restrict__ kp) {
  const int b = blockIdx.y;
  const int id = blockIdx.x * 256 + threadIdx.x;       // < CHUNKS_PB
  const int li = id & 15, g = (id >> 4) & 3, ktp = (id >> 6) & 31,
            nt = (id >> 11) & 1, it = id >> 12;
  const int n = it * 32 + nt * 16 + li;
  const int d = ktp * 32 + g * 8;
  float4v f0 = {0.f, 0.f, 0.f, 0.f}, f1 = {0.f, 0.f, 0.f, 0.f};
  if (n < LL) {
    const float* src = (n < PP) ? prefix_k + (size_t)n * HH + d
                                : key + ((size_t)b * SS + (n - PP)) * HH + d;
    f0 = *(const float4v*)src; f1 = *(const float4v*)(src + 4);
  }
  *(half8v*)(kp + ((size_t)b * CHUNKS_PB + id) * 8) = cvt8h(f0, f1);
}

__global__ __launch_bounds__(256) void conv_v(const float* __restrict__ prefix_v,
                                              const float* __restrict__ value,
                                              _Float16* __restrict__ vp) {
  const int b = blockIdx.y;
  const int id = blockIdx.x * 256 + threadIdx.x;
  const int d = id & 1023, g = (id >> 10) & 3, it = id >> 12;
  const int nb = it * 32 + g * 8;
  half8v h;
  #pragma unroll
  for (int j = 0; j < 8; ++j) {
    int n = nb + j;
    float f = 0.f;
    if (n < LL)
      f = (n < PP) ? prefix_v[(size_t)n * HH + d]
                   : value[((size_t)b * SS + (n - PP)) * HH + d];
    h[j] = (_Float16)f;
  }
  *(half8v*)(vp + ((size_t)b * CHUNKS_PB + id) * 8) = h;
}

// ---------------- fused flash attention, v13: v7 structure, 2 blocks/CU ----------------
// v7 per-wave structure (8 waves, D-128/wave, M=32, 1 barrier/iter, 3-deep
// pipeline, DPP softmax, named LDS banks) with:
//  - sbuf stride 36->34: LDS 75.1 KB so TWO blocks fit per CU (R12 proved this
//    unlocks occupancy 23->45%)
//  - __launch_bounds__(512,2): this compiler reads arg2 as min BLOCKS/CU
//    (R12: arg=4 -> 64-reg cap -> spill). arg=2 -> cap 128 >= natural 120.
template<int PATH>
__global__ __launch_bounds__(512, 2) void attn_fused(
    const float* __restrict__ q,
    const float* __restrict__ key,
    const float* __restrict__ value,
    const float* __restrict__ prefix_k,
    const float* __restrict__ prefix_v,
    const _Float16* __restrict__ kp,
    const _Float16* __restrict__ vp,
    float* __restrict__ out)
{
  __shared__ __align__(16) float sbuf0[8][32][34];        // 34.8 KB, bank 0 (even tiles)
  __shared__ __align__(16) float sbuf1[8][32][34];        // bank 1 (odd tiles)
  __shared__ __align__(16) unsigned short Pl0[32][40];
  __shared__ __align__(16) unsigned short Pl1[32][40];
  __shared__ float sc0[32], sc1[32];
  __shared__ float l_l[32];

  const int tid = threadIdx.x;
  const int w = tid >> 6, ln = tid & 63, g = ln >> 4, li = ln & 15;
  const int bid = blockIdx.x, xcd = bid & 7, b = xcd >> 1;
  const int qt = ((bid >> 3) << 1) | (xcd & 1);
  const int q0 = qt * 32;
  const int dbase = w * 128;

  // Q fragments fp16: A-layout row=li, k=g*8+j
  half8v qf[2][4];
  #pragma unroll
  for (int mt = 0; mt < 2; ++mt)
    #pragma unroll
    for (int kt = 0; kt < 4; ++kt) {
      const float* p = q + ((size_t)(b * SS + q0 + mt * 16 + li)) * HH + dbase + kt * 32 + g * 8;
      qf[mt][kt] = cvt8h(*(const float4v*)p, *(const float4v*)(p + 4));
    }

  float4v z4 = {0.f, 0.f, 0.f, 0.f};
  float4v o[2][8];
  #pragma unroll
  for (int mt = 0; mt < 2; ++mt)
    #pragma unroll
    for (int dt = 0; dt < 8; ++dt) o[mt][dt] = z4;
  float m_r = -1e30f, l_r = 0.f;

  const _Float16* kbase = kp + ((size_t)b * CHUNKS_PB + (size_t)(w * 4) * 64 + g * 16 + li) * 8;
  const _Float16* vbase = vp + ((size_t)b * CHUNKS_PB + (size_t)g * 1024 + dbase + li) * 8;

  half8v kreg[8];   // K(i) during iter i
  half8v vreg[8];   // V(i-2) during iter i
  if constexpr (PATH == 0) {
    #pragma unroll
    for (int kt = 0; kt < 4; ++kt)
      #pragma unroll
      for (int nt = 0; nt < 2; ++nt)
        kreg[kt * 2 + nt] = *(const half8v*)(kbase + (size_t)(nt * 2048 + kt * 64) * 8);
  }

  const int srow = w * 4 + (ln >> 4);     // slab row this lane helps with
  const int c0 = (ln & 15) * 2;

  // ---- phase helpers; bank arrays passed as compile-time-known pointers ----
  auto do_qk = [&](int i, float (*sb)[32][34]) __attribute__((always_inline)) {
    float4v sacc[2][2];
    sacc[0][0] = z4; sacc[0][1] = z4; sacc[1][0] = z4; sacc[1][1] = z4;
    #pragma unroll
    for (int kt = 0; kt < 4; ++kt) {
      half8v kb[2];
      if constexpr (PATH == 0) {
        kb[0] = kreg[kt * 2 + 0]; kb[1] = kreg[kt * 2 + 1];
      } else {
        #pragma unroll
        for (int nt = 0; nt < 2; ++nt) {
          int n = i * 32 + nt * 16 + li;
          int nc = (n < LL) ? n : 0;
          const float* kpp = (nc < PP) ? (prefix_k + (size_t)nc * HH)
                                       : (key + ((size_t)b * SS + (nc - PP)) * HH);
          kpp += dbase + kt * 32 + g * 8;
          kb[nt] = cvt8h(*(const float4v*)kpp, *(const float4v*)(kpp + 4));
        }
      }
      #pragma unroll
      for (int mt = 0; mt < 2; ++mt)
        #pragma unroll
        for (int nt = 0; nt < 2; ++nt)
          sacc[mt][nt] = __builtin_amdgcn_mfma_f32_16x16x32_f16(qf[mt][kt], kb[nt], sacc[mt][nt], 0, 0, 0);
    }
    // C/D: row = g*4+r, col = li
    #pragma unroll
    for (int mt = 0; mt < 2; ++mt)
      #pragma unroll
      for (int nt = 0; nt < 2; ++nt)
        #pragma unroll
        for (int r = 0; r < 4; ++r)
          sb[w][mt * 16 + g * 4 + r][nt * 16 + li] = sacc[mt][nt][r];
    // prefetch kreg <- K(i+1)  (benign 1-tile overrun into vp after last tile)
    if constexpr (PATH == 0) {
      kbase += TILE_ELEMS;
      #pragma unroll
      for (int kt = 0; kt < 4; ++kt)
        #pragma unroll
        for (int nt = 0; nt < 2; ++nt)
          kreg[kt * 2 + nt] = *(const half8v*)(kbase + (size_t)(nt * 2048 + kt * 64) * 8);
    }
  };

  auto do_softmax = [&](int t, const float (*sb)[32][34],
                        unsigned short (*plw)[40], float* scw)
      __attribute__((always_inline)) {
    float s0 = 0.f, s1 = 0.f;
    #pragma unroll
    for (int bw = 0; bw < 8; ++bw) {
      float2 tv = *(const float2*)&sb[bw][srow][c0];
      s0 += tv.x; s1 += tv.y;
    }
    if constexpr (PATH == 1) {
      if (t * 32 + c0 >= LL)     s0 = -1e30f;
      if (t * 32 + c0 + 1 >= LL) s1 = -1e30f;
    }
    const float mx = row16_max(fmaxf(s0, s1));      // DPP, VALU pipe
    const float m_new = fmaxf(m_r, mx);
    const float scp = exp2f((m_r - m_new) * LOG2E);
    const float p0 = exp2f((s0 - m_new) * LOG2E);
    const float p1 = exp2f((s1 - m_new) * LOG2E);
    const float ts = row16_sum(p0 + p1);            // DPP, VALU pipe
    l_r = l_r * scp + ts;
    m_r = m_new;
    *(unsigned*)&plw[srow][c0] = pack2h(p0, p1);
    if ((ln & 15) == 0) scw[srow] = scp;
  };

  auto do_pv = [&](int t, const unsigned short (*plr)[40], const float* scr)
      __attribute__((always_inline)) {
    float scc[2][4];
    #pragma unroll
    for (int mt = 0; mt < 2; ++mt)
      #pragma unroll
      for (int r = 0; r < 4; ++r)
        scc[mt][r] = scr[mt * 16 + g * 4 + r];
    #pragma unroll
    for (int mt = 0; mt < 2; ++mt)
      #pragma unroll
      for (int dt = 0; dt < 8; ++dt)
        #pragma unroll
        for (int r = 0; r < 4; ++r)
          o[mt][dt][r] *= scc[mt][r];
    half8v pa0 = *(const half8v*)&plr[li][g * 8];
    half8v pa1 = *(const half8v*)&plr[16 + li][g * 8];
    #pragma unroll
    for (int dt = 0; dt < 8; ++dt) {
      half8v vb;
      if constexpr (PATH == 0) {
        vb = vreg[dt];
      } else {
        const int d = dbase + dt * 16 + li;
        #pragma unroll
        for (int j = 0; j < 8; ++j) {
          int n = t * 32 + g * 8 + j;
          int nc = (n < LL) ? n : 0;    // clamped rows have P==0
          float f = (nc < PP) ? prefix_v[(size_t)nc * HH + d]
                              : value[((size_t)b * SS + (nc - PP)) * HH + d];
          vb[j] = (_Float16)f;
        }
      }
      o[0][dt] = __builtin_amdgcn_mfma_f32_16x16x32_f16(pa0, vb, o[0][dt], 0, 0, 0);
      o[1][dt] = __builtin_amdgcn_mfma_f32_16x16x32_f16(pa1, vb, o[1][dt], 0, 0, 0);
    }
  };

  auto load_v = [&]() __attribute__((always_inline)) {
    if constexpr (PATH == 0) {
      #pragma unroll
      for (int dt = 0; dt < 8; ++dt)
        vreg[dt] = *(const half8v*)(vbase + (size_t)(dt * 16) * 8);
      vbase += TILE_ELEMS;
    }
  };

  // ---- pipeline: prologue / steady (x2 unrolled) / epilogue ----
  // parity: qk(i)->sbuf(i&1); sm(t): reads sbuf(t&1), writes Pl(t&1)/sc(t&1);
  //         pv(t): reads Pl(t&1)/sc(t&1), consumes vreg=V(t).
  // region order: QK -> PV -> softmax (PV independent of this iter's softmax).
  do_qk(0, sbuf0);
  LGKM_BAR();
  do_qk(1, sbuf1); do_softmax(0, sbuf0, Pl0, sc0); load_v();
  LGKM_BAR();
  int i = 2;
  for (; i + 1 < NTILES; i += 2) {
    do_qk(i, sbuf0);
    do_pv(i - 2, Pl0, sc0);
    do_softmax(i - 1, sbuf1, Pl1, sc1);
    load_v();
    LGKM_BAR();
    do_qk(i + 1, sbuf1);
    do_pv(i - 1, Pl1, sc1);
    do_softmax(i, sbuf0, Pl0, sc0);
    load_v();
    LGKM_BAR();
  }
  // NTILES odd: one remaining even-bank steady iter (i == NTILES-1 == 128)
  do_qk(NTILES - 1, sbuf0);
  do_pv(NTILES - 3, Pl0, sc0);
  do_softmax(NTILES - 2, sbuf1, Pl1, sc1);
  load_v();
  LGKM_BAR();
  // epilogue
  do_pv(NTILES - 2, Pl1, sc1);
  do_softmax(NTILES - 1, sbuf0, Pl0, sc0);
  load_v();
  LGKM_BAR();
  do_pv(NTILES - 1, Pl0, sc0);

  // ---- finalize ----
  if ((ln & 15) == 0) l_l[srow] = l_r;
  LGKM_BAR();
  float il[2][4];
  #pragma unroll
  for (int mt = 0; mt < 2; ++mt)
    #pragma unroll
    for (int r = 0; r < 4; ++r)
      il[mt][r] = 1.0f / l_l[mt * 16 + g * 4 + r];
  #pragma unroll
  for (int mt = 0; mt < 2; ++mt)
    #pragma unroll
    for (int dt = 0; dt < 8; ++dt)
      #pragma unroll
      for (int r = 0; r < 4; ++r)
        out[((size_t)(b * SS + q0 + mt * 16 + g * 4 + r)) * HH + dbase + dt * 16 + li]
            = o[mt][dt][r] * il[mt][r];
}

extern "C" void kernel_launch(void* const* d_in, const int* in_sizes, int n_in,
                              void* d_out, int out_size, void* d_ws, size_t ws_size,
                              hipStream_t stream) {
  const float* q        = (const float*)d_in[0];
  const float* key      = (const float*)d_in[1];
  const float* value    = (const float*)d_in[2];
  const float* prefix_k = (const float*)d_in[3];
  const float* prefix_v = (const float*)d_in[4];
  float* out = (float*)d_out;

  const size_t PLANE = (size_t)BB * CHUNKS_PB * 8;              // fp16 elems per plane
  const size_t NEED  = 2 * PLANE * sizeof(unsigned short);      // 67.6 MB

  if (ws_size >= NEED) {
    _Float16* kp = (_Float16*)d_ws;
    _Float16* vp = kp + PLANE;
    conv_k<<<dim3(CHUNKS_PB / 256, BB), 256, 0, stream>>>(prefix_k, key, kp);
    conv_v<<<dim3(CHUNKS_PB / 256, BB), 256, 0, stream>>>(prefix_v, value, vp);
    attn_fused<0><<<512, 512, 0, stream>>>(q, key, value, prefix_k, prefix_v, kp, vp, out);
  } else {
    attn_fused<1><<<512, 512, 0, stream>>>(q, key, value, prefix_k, prefix_v,
                                           nullptr, nullptr, out);
  }
}